// Round 1
// baseline (211.582 us; speedup 1.0000x reference)
//
#include <hip/hip_runtime.h>

// Problem constants (match reference setup_inputs):
//   NTOK=50257, NINP=512, NREL=200, N=1024, L=64, EPS=32, E=32768
#define NINP 512
#define NREL 200

__global__ __launch_bounds__(256) void fused_loss_kernel(
    const int* __restrict__ seq,    // (N, L)
    const int* __restrict__ rel,    // (E,)
    const float* __restrict__ emb,  // (NTOK, NINP)
    const float* __restrict__ W,    // (NREL, NINP)
    const float* __restrict__ bias, // (NREL,)
    float* __restrict__ out,        // [2] : logp, acc  (must be pre-zeroed)
    int N, int L, int eps)
{
    __shared__ float h_lds[NINP];
    __shared__ int   toks[64];
    __shared__ unsigned int maskbits[7];   // 224 bits >= NREL=200
    __shared__ float red_logp[4];
    __shared__ float red_acc[4];

    const int i = blockIdx.x;
    const int t = threadIdx.x;

    // stage token ids + zero the mask bitset
    if (t < L)  toks[t] = seq[i * L + t];
    if (t < 7)  maskbits[t] = 0u;
    __syncthreads();

    // ---- Phase A: h[i] = sum_k emb[seq[i,k]]  (coalesced float2 per thread) ----
    float2 acc2 = make_float2(0.f, 0.f);
    for (int k = 0; k < L; ++k) {
        const float2* row = (const float2*)(emb + (long)toks[k] * NINP);
        float2 v = row[t];           // 256 threads x 8B = 2KB contiguous
        acc2.x += v.x;
        acc2.y += v.y;
    }
    h_lds[2 * t]     = acc2.x;
    h_lds[2 * t + 1] = acc2.y;

    // ---- Phase B: relation bitmask for this sequence's edges ----
    if (t < eps) {
        int r = rel[i * eps + t];
        atomicOr(&maskbits[r >> 5], 1u << (r & 31));
    }
    __syncthreads();

    // ---- Phase C: logit[r] = b[r] + h . W[r]; loss + accuracy terms ----
    float term  = 0.f;
    float match = 0.f;
    if (t < NREL) {
        float dot = bias[t];
        const float4* wrow = (const float4*)(W + (long)t * NINP);
        const float4* hv   = (const float4*)h_lds;
        #pragma unroll 8
        for (int k = 0; k < NINP / 4; ++k) {
            float4 w = wrow[k];
            float4 h = hv[k];        // same address across lanes -> LDS broadcast
            dot += w.x * h.x + w.y * h.y + w.z * h.z + w.w * h.w;
        }
        const unsigned mb = (maskbits[t >> 5] >> (t & 31)) & 1u;
        if (mb) {
            // log_sigmoid(x) = min(x,0) - log1p(exp(-|x|))  (stable)
            term = fminf(dot, 0.f) - log1pf(expf(-fabsf(dot)));
        } else {
            // log(1 + 1e-5 - sigmoid(x)) = log(1e-5 + sigmoid(-x))
            float sneg = 1.f / (1.f + expf(dot));   // sigmoid(-x)
            term = logf(1e-5f + sneg);
        }
        match = (((dot > 0.5f) ? 1u : 0u) == mb) ? 1.f : 0.f;
    }

    // ---- block reduction: 4 waves of 64 ----
    #pragma unroll
    for (int off = 32; off > 0; off >>= 1) {
        term  += __shfl_down(term,  off);
        match += __shfl_down(match, off);
    }
    const int wave = t >> 6;
    const int lane = t & 63;
    if (lane == 0) { red_logp[wave] = term; red_acc[wave] = match; }
    __syncthreads();
    if (t == 0) {
        float s = red_logp[0] + red_logp[1] + red_logp[2] + red_logp[3];
        float a = red_acc[0]  + red_acc[1]  + red_acc[2]  + red_acc[3];
        atomicAdd(out + 0, s / (float)N);
        atomicAdd(out + 1, a / ((float)N * (float)NREL));
    }
}

extern "C" void kernel_launch(void* const* d_in, const int* in_sizes, int n_in,
                              void* d_out, int out_size, void* d_ws, size_t ws_size,
                              hipStream_t stream) {
    const int*   seq = (const int*)d_in[0];
    const int*   m   = (const int*)d_in[1]; (void)m;  // constant EPS per sequence
    const int*   rel = (const int*)d_in[2];
    const float* emb = (const float*)d_in[3];
    const float* W   = (const float*)d_in[4];
    const float* b   = (const float*)d_in[5];
    float* out = (float*)d_out;

    const int N   = in_sizes[1];               // 1024
    const int L   = in_sizes[0] / N;           // 64
    const int eps = in_sizes[2] / N;           // 32

    hipMemsetAsync(out, 0, 2 * sizeof(float), stream);
    fused_loss_kernel<<<N, 256, 0, stream>>>(seq, rel, emb, W, b, out, N, L, eps);
}